// Round 4
// baseline (232.819 us; speedup 1.0000x reference)
//
#include <hip/hip_runtime.h>
#include <math.h>

// (B, CK, CV, T, H, W) = (2, 64, 256, 8, 48, 48)
#define NB 2
#define CKD 64
#define CVD 256
#define TD 8
#define HWD 2304
#define THWD 18432
#define QB 32
#define NQB (HWD / QB)    // 72
#define KVT 64            // kv per tile
#define SPLIT 8
#define TILES (THWD / SPLIT / KVT)  // 36

typedef __bf16 bf16_t;
typedef __bf16 bf16x8 __attribute__((ext_vector_type(8)));
typedef __bf16 bf16x4 __attribute__((ext_vector_type(4)));
typedef float f32x4 __attribute__((ext_vector_type(4)));
typedef unsigned int u32;

__device__ __forceinline__ void gload16(const void* g, void* l) {
    __builtin_amdgcn_global_load_lds((const __attribute__((address_space(1))) u32*)g,
                                     (__attribute__((address_space(3))) u32*)l, 16, 0, 0);
}

// ---------------------------------------------------------------------------
// prep_kf: KF2 tiled: element (kv, ch) ch in [0,128): mk (ch<64) | mk^2.
//   byte = ((b*1152 + kv/16)*16 + kv%16)*256 + ((G ^ (kv&7))<<4) + (ch%8)*2
// ---------------------------------------------------------------------------
__global__ void prep_kf(const float* __restrict__ mk, char* __restrict__ KF2) {
    __shared__ float tile[64][65];
    const int b = blockIdx.y;
    const int kv0 = blockIdx.x * 64;
    const int tid = threadIdx.x;
    {
        const int c = tid >> 2, seg = tid & 3;
        const float* src = mk + ((size_t)b * CKD + c) * THWD + kv0;
#pragma unroll
        for (int j = 0; j < 4; ++j) {
            int ch = seg + j * 4;
            f32x4 v = *(const f32x4*)(src + ch * 4);
#pragma unroll
            for (int x = 0; x < 4; ++x) tile[c][ch * 4 + x] = v[x];
        }
    }
    __syncthreads();
#pragma unroll
    for (int k = 0; k < 4; ++k) {
        int gid = k * 256 + tid;        // 1024 granules: 64 kv x 16 G
        int kvl = gid >> 4, G = gid & 15;
        bf16x8 o;
#pragma unroll
        for (int e = 0; e < 8; ++e) {
            int ch = G * 8 + e;
            float v;
            if (ch < 64) v = tile[ch][kvl];
            else { float m = tile[ch - 64][kvl]; v = m * m; }
            o[e] = (bf16_t)v;
        }
        size_t byte = (((size_t)b * (THWD / 16) + ((kv0 + kvl) >> 4)) * 16 + (kvl & 15)) * 256 +
                      (size_t)((G ^ (kvl & 7)) << 4);
        *(bf16x8*)(KF2 + byte) = o;
    }
}

// ---------------------------------------------------------------------------
// prep_qf: QF2 tiled: element (q, ch): 2*qk*qe (ch<64) | -qe (ch>=64)
//   byte = (((b*144 + q/16)*4 + ks)*16 + q%16)*64 + G2*16 ;  ch = ks*32+G2*8+e
// bsq[b][q] = sum_ch qe*qk*qk (fp32)
// ---------------------------------------------------------------------------
__global__ void prep_qf(const float* __restrict__ qk, const float* __restrict__ qe,
                        char* __restrict__ QF2, float* __restrict__ bsq) {
    __shared__ float tk[64][65];
    __shared__ float te[64][65];
    __shared__ float bs[4][64];
    const int b = blockIdx.y;
    const int q0 = blockIdx.x * 64;
    const int tid = threadIdx.x;
    {
        const int c = tid >> 2, seg = tid & 3;
        const float* s1 = qk + ((size_t)b * CKD + c) * HWD + q0;
        const float* s2 = qe + ((size_t)b * CKD + c) * HWD + q0;
#pragma unroll
        for (int j = 0; j < 4; ++j) {
            int ch = seg + j * 4;
            f32x4 v1 = *(const f32x4*)(s1 + ch * 4);
            f32x4 v2 = *(const f32x4*)(s2 + ch * 4);
#pragma unroll
            for (int x = 0; x < 4; ++x) { tk[c][ch * 4 + x] = v1[x]; te[c][ch * 4 + x] = v2[x]; }
        }
    }
    __syncthreads();
    {
        int qls = tid & 63, cp = tid >> 6;
        float s = 0.f;
#pragma unroll
        for (int cc = 0; cc < 16; ++cc) {
            int ch = cp * 16 + cc;
            float kk = tk[ch][qls];
            s = fmaf(te[ch][qls] * kk, kk, s);
        }
        bs[cp][qls] = s;
    }
#pragma unroll
    for (int k = 0; k < 4; ++k) {
        int gid = k * 256 + tid;
        int qll = gid >> 4, G = gid & 15;
        int ks = G >> 2, G2 = G & 3;
        bf16x8 o;
#pragma unroll
        for (int e = 0; e < 8; ++e) {
            int ch = G * 8 + e;
            float v;
            if (ch < 64) v = 2.f * tk[ch][qll] * te[ch][qll];
            else v = -te[ch - 64][qll];
            o[e] = (bf16_t)v;
        }
        size_t byte = ((((size_t)b * (HWD / 16) + blockIdx.x * 4 + (qll >> 4)) * 4 + ks) * 16 +
                       (qll & 15)) * 64 + (size_t)(G2 << 4);
        *(bf16x8*)(QF2 + byte) = o;
    }
    __syncthreads();
    if (tid < 64) bsq[b * HWD + q0 + tid] = bs[0][tid] + bs[1][tid] + bs[2][tid] + bs[3][tid];
}

// ---------------------------------------------------------------------------
// mv_t: mv fp32 [b][cv][thw] -> mvT bf16 tiled per 32-kv group with the
// strip-interleaved kv order that matches the PV B-fragment packing:
//   slot (G, e) <-> kv_local = (e>>2)*16 + G*4 + (e&3)
//   byte = ((b*576 + kv32)*256 + cv)*64 + G*16
// ---------------------------------------------------------------------------
__global__ void mv_t(const float* __restrict__ mv, char* __restrict__ mvT) {
    __shared__ float tile[64][65];
    const int b = blockIdx.z;
    const int cv0 = blockIdx.y * 64;
    const int kv0 = blockIdx.x * 64;
    const int tid = threadIdx.x;
    {
        const int cvl = tid >> 2, seg = tid & 3;
        const float* src = mv + ((size_t)b * CVD + cv0 + cvl) * THWD + kv0;
#pragma unroll
        for (int j = 0; j < 4; ++j) {
            int ch = seg + j * 4;
            f32x4 v = *(const f32x4*)(src + ch * 4);
#pragma unroll
            for (int x = 0; x < 4; ++x) tile[cvl][ch * 4 + x] = v[x];
        }
    }
    __syncthreads();
#pragma unroll
    for (int k = 0; k < 2; ++k) {
        int gid = k * 256 + tid;        // 512 granules: 64 cv x (2 t32 x 4 G)
        int cvl = gid >> 3, gseg = gid & 7;
        int t32l = gseg >> 2, G = gseg & 3;
        bf16x8 o;
#pragma unroll
        for (int e = 0; e < 8; ++e)
            o[e] = (bf16_t)tile[cvl][t32l * 32 + (e >> 2) * 16 + G * 4 + (e & 3)];
        size_t byte = (((size_t)b * (THWD / 32) + (kv0 >> 5) + t32l) * 256 + cv0 + cvl) * 64 +
                      (size_t)(G << 4);
        *(bf16x8*)(mvT + byte) = o;
    }
}

// ---------------------------------------------------------------------------
// fused: 256 thr = 4 waves = (s = kv-half) x (c = cv-half / strip parity).
// Per 64-kv tile: wave computes QK for strip st=2s+c (K=128 MFMA), exp,
// writes its 16x32 w-quarter to the small w_lds; reads back packed K=32
// B-frags for PV over (kv-half s, cv-half c). mv comes straight from L2.
// Split-T partials are plain sums (scores <= 0, no softmax max needed).
// ---------------------------------------------------------------------------
__global__ __launch_bounds__(256, 3) void fused(
    const char* __restrict__ KF2, const char* __restrict__ QF2,
    const char* __restrict__ mvT, const float* __restrict__ ms,
    const float* __restrict__ bsq, float* __restrict__ accP,
    float* __restrict__ lP) {
    __shared__ __align__(16) char kf_s[2][16384];
    __shared__ __align__(16) char w_lds[4096];   // [2 s][32 q][4 g][2 p] * 8B
    __shared__ float l_s[4][QB];

    const int tid = threadIdx.x;
    const int lane = tid & 63;
    const int wave = tid >> 6;
    const int s = wave >> 1;
    const int c = wave & 1;
    const int st = s * 2 + c;
    const int r = lane & 15;
    const int g = lane >> 4;

    // XCD swizzle: 1152 blocks, 144 consecutive ids per XCD = one sp slice
    const int bid = blockIdx.x;
    const int id = (bid & 7) * (NB * NQB) + (bid >> 3);
    const int sp = id / (NB * NQB);
    const int rem = id % (NB * NQB);
    const int b = rem / NQB;
    const int qblk = rem % NQB;
    const int tbase = sp * (THWD / SPLIT);

    const char* KFb = KF2 + (size_t)b * THWD * 256;
    const char* QFb = QF2 + (size_t)b * (HWD / 16) * 4096;
    const char* mvTb = mvT + (size_t)b * (THWD / 32) * 16384;
    const float* msb = ms + (size_t)b * THWD;

    // resident query B-frags + bsq
    bf16x8 qf[2][4];
    float bsqr[2];
#pragma unroll
    for (int ql = 0; ql < 2; ++ql) {
        int qb16 = qblk * 2 + ql;
#pragma unroll
        for (int ks = 0; ks < 4; ++ks)
            qf[ql][ks] = *(const bf16x8*)(QFb + ((size_t)qb16 * 4 + ks) * 1024 + r * 64 + g * 16);
        bsqr[ql] = bsq[b * HWD + qblk * QB + ql * 16 + r];
    }

    f32x4 acc[8][2];
#pragma unroll
    for (int i = 0; i < 8; ++i)
#pragma unroll
        for (int j = 0; j < 2; ++j) acc[i][j] = (f32x4){0.f, 0.f, 0.f, 0.f};
    float lacc[2] = {0.f, 0.f};

    auto stage = [&](int buf, int t0) {
        const char* gk = KFb + (size_t)t0 * 256 + wave * 4096 + lane * 16;
        char* lk = &kf_s[buf][wave * 4096];
#pragma unroll
        for (int i = 0; i < 4; ++i) gload16(gk + i * 1024, lk + i * 1024);
    };
    stage(0, tbase);

#pragma unroll 2
    for (int it = 0; it < TILES; ++it) {
        const int t0 = tbase + it * KVT;
        const char* kf_c = kf_s[it & 1];

        // staging of tile it landed; all reads of prev tile / w_lds complete
        asm volatile("s_waitcnt vmcnt(0) lgkmcnt(0)" ::: "memory");
        __builtin_amdgcn_s_barrier();

        // mv fragments for this tile: direct global (L2-resident), issued
        // first so the compiler's counted vmcnt for them excludes the stage
        bf16x8 mvf[8];
#pragma unroll
        for (int cvt = 0; cvt < 8; ++cvt)
            mvf[cvt] = *(const bf16x8*)(mvTb +
                ((size_t)((t0 >> 5) + s) * 256 + c * 128 + cvt * 16 + r) * 64 + g * 16);
        f32x4 msc = *(const f32x4*)(msb + t0 + st * 16 + g * 4);

        if (it + 1 < TILES) stage((it + 1) & 1, t0 + KVT);

        // QK for strip st: S[ql][i] = dot for (kv = t0+st*16+g*4+i, q = ql*16+r)
        f32x4 S[2];
        S[0] = (f32x4){0.f, 0.f, 0.f, 0.f};
        S[1] = (f32x4){0.f, 0.f, 0.f, 0.f};
#pragma unroll
        for (int ks = 0; ks < 4; ++ks) {
            bf16x8 kff = *(const bf16x8*)(kf_c + (st * 16 + r) * 256 +
                                          (((ks * 4 + g) ^ (r & 7)) << 4));
#pragma unroll
            for (int ql = 0; ql < 2; ++ql)
                S[ql] = __builtin_amdgcn_mfma_f32_16x16x32_bf16(kff, qf[ql][ks], S[ql], 0, 0, 0);
        }

        // w = exp((S - bsq) * ms/8)  (scores <= 0: no max bookkeeping)
#pragma unroll
        for (int ql = 0; ql < 2; ++ql) {
            f32x4 sv = S[ql];
            float w0 = __expf((sv[0] - bsqr[ql]) * (msc[0] * 0.125f));
            float w1 = __expf((sv[1] - bsqr[ql]) * (msc[1] * 0.125f));
            float w2 = __expf((sv[2] - bsqr[ql]) * (msc[2] * 0.125f));
            float w3 = __expf((sv[3] - bsqr[ql]) * (msc[3] * 0.125f));
            lacc[ql] += (w0 + w1) + (w2 + w3);
            bf16x4 wb;
            wb[0] = (bf16_t)w0; wb[1] = (bf16_t)w1; wb[2] = (bf16_t)w2; wb[3] = (bf16_t)w3;
            *(bf16x4*)(&w_lds[((s * 32 + ql * 16 + r) * 4 + g) * 16 + c * 8]) = wb;
        }
        asm volatile("s_waitcnt lgkmcnt(0)" ::: "memory");
        __builtin_amdgcn_s_barrier();

        // PV: acc[cv][q] += mv[cv][kv-half s] * w[kv-half s][q], K=32
        bf16x8 wf[2];
#pragma unroll
        for (int ql = 0; ql < 2; ++ql)
            wf[ql] = *(const bf16x8*)(&w_lds[((s * 32 + ql * 16 + r) * 4 + g) * 16]);
#pragma unroll
        for (int cvt = 0; cvt < 8; ++cvt)
#pragma unroll
            for (int ql = 0; ql < 2; ++ql)
                acc[cvt][ql] = __builtin_amdgcn_mfma_f32_16x16x32_bf16(
                    mvf[cvt], wf[ql], acc[cvt][ql], 0, 0, 0);
    }

    // epilogue: reduce the s-pair via retired kf_s, write partials
    __syncthreads();
    float* red = (float*)&kf_s[0][0];
    if (s == 1) {
#pragma unroll
        for (int cvt = 0; cvt < 8; ++cvt)
#pragma unroll
            for (int ql = 0; ql < 2; ++ql)
                *(f32x4*)(red + c * 4096 + ((cvt * 2 + ql) * 256 + lane * 4)) = acc[cvt][ql];
    }
#pragma unroll
    for (int ql = 0; ql < 2; ++ql) {
        float v = lacc[ql];
        v += __shfl_xor(v, 16);
        v += __shfl_xor(v, 32);
        if (lane < 16) l_s[wave][ql * 16 + lane] = v;
    }
    __syncthreads();
    size_t pb = (size_t)(b * NQB + qblk) * SPLIT + sp;
    if (s == 0) {
        float* accB = accP + pb * (CVD * QB);
#pragma unroll
        for (int cvt = 0; cvt < 8; ++cvt)
#pragma unroll
            for (int ql = 0; ql < 2; ++ql) {
                f32x4 o = acc[cvt][ql] +
                          *(const f32x4*)(red + c * 4096 + ((cvt * 2 + ql) * 256 + lane * 4));
                int cv0 = c * 128 + cvt * 16 + g * 4;
                int q = ql * 16 + r;
                *(f32x4*)(accB + ((size_t)(cv0 >> 2) * QB + q) * 4) = o;
            }
    }
    if (tid < QB)
        lP[pb * QB + tid] = (l_s[0][tid] + l_s[1][tid]) + (l_s[2][tid] + l_s[3][tid]);
}

// ---------------------------------------------------------------------------
// combine: sum split partials (f32x4-coalesced layout), divide, blend.
// ---------------------------------------------------------------------------
__global__ void combine2(const float* __restrict__ accP, const float* __restrict__ lP,
                         const float* __restrict__ mv, const float* __restrict__ up,
                         float* __restrict__ out) {
    int idx = blockIdx.x * 256 + threadIdx.x;   // (b, qblk, cvq4, nl)
    int nl = idx & 31;
    int t = idx >> 5;
    int cvq4 = t & 63;
    int t2 = t >> 6;
    int qblk = t2 % NQB;
    int b = t2 / NQB;
    size_t pb0 = (size_t)(b * NQB + qblk) * SPLIT;
    const float* base = accP + pb0 * (CVD * QB) + ((size_t)cvq4 * QB + nl) * 4;
    f32x4 a = {0.f, 0.f, 0.f, 0.f};
    float l = 0.f;
#pragma unroll
    for (int sp = 0; sp < SPLIT; ++sp) {
        a += *(const f32x4*)(base + (size_t)sp * (CVD * QB));
        l += lP[(pb0 + sp) * QB + nl];
    }
    int n = qblk * QB + nl;
    int cv0 = cvq4 * 4;
    float p = up[b * HWD + n];
    float rl = 1.f / l;
#pragma unroll
    for (int e = 0; e < 4; ++e) {
        float last = mv[((size_t)b * CVD + cv0 + e) * THWD + (TD - 1) * HWD + n];
        out[((size_t)b * CVD + cv0 + e) * HWD + n] = a[e] * rl * p + last * (1.f - p);
    }
}

// ---------------------------------------------------------------------------
extern "C" void kernel_launch(void* const* d_in, const int* in_sizes, int n_in,
                              void* d_out, int out_size, void* d_ws,
                              size_t ws_size, hipStream_t stream) {
    const float* qk = (const float*)d_in[0];
    const float* qe = (const float*)d_in[1];
    const float* mk = (const float*)d_in[2];
    const float* ms = (const float*)d_in[3];
    const float* mv = (const float*)d_in[4];
    const float* up = (const float*)d_in[5];
    float* out = (float*)d_out;

    char* ws = (char*)d_ws;
    size_t off = 0;
    auto alloc = [&](size_t bytes) {
        size_t o = off;
        off += (bytes + 255) & ~(size_t)255;
        return o;
    };
    size_t kf_o = alloc((size_t)NB * THWD * 256);            // 9.4 MB
    size_t qf_o = alloc((size_t)NB * (HWD / 16) * 4096);     // 1.2 MB
    size_t mvt_o = alloc((size_t)NB * (THWD / 32) * 16384);  // 18.9 MB
    size_t bsq_o = alloc((size_t)NB * HWD * 4);
    size_t lp_o = alloc((size_t)NB * NQB * SPLIT * QB * 4);
    size_t acc_o = alloc((size_t)NB * NQB * SPLIT * CVD * QB * 4);  // 37.7 MB

    char* KF2 = ws + kf_o;
    char* QF2 = ws + qf_o;
    char* MVT = ws + mvt_o;
    float* bsqp = (float*)(ws + bsq_o);
    float* lPp = (float*)(ws + lp_o);
    float* accPp = (float*)(ws + acc_o);

    prep_kf<<<dim3(THWD / 64, NB), 256, 0, stream>>>(mk, KF2);
    prep_qf<<<dim3(HWD / 64, NB), 256, 0, stream>>>(qk, qe, QF2, bsqp);
    mv_t<<<dim3(THWD / 64, CVD / 64, NB), 256, 0, stream>>>(mv, MVT);

    fused<<<NB * NQB * SPLIT, 256, 0, stream>>>(KF2, QF2, MVT, ms, bsqp, accPp, lPp);

    combine2<<<(NB * NQB * 64 * 32) / 256, 256, 0, stream>>>(accPp, lPp, mv, up, out);
}